// Round 1
// baseline (1463.642 us; speedup 1.0000x reference)
//
#include <hip/hip_runtime.h>

// FeatureProcessingBlock: per 64x64 window, Out = sum_t Cs_t^T ( Hs_t^T @ X_c @ Ws_t )
// x: (4,48,512,512) f32, Ws/Hs: (3,64,64) f32, Cs: (3,48,48) f32, out f32.
// Fused single kernel: workgroup = (window, W'-tile of 16), 512 threads, grid 1024.
// Stages A (contract w) / B (contract h): bf16 MFMA 16x16x32.
// Stage C (contract c): VALU float2 FMA into 96 reg accumulators/thread.

typedef __attribute__((ext_vector_type(8))) short short8;
typedef __attribute__((ext_vector_type(4))) short short4v;
typedef __attribute__((ext_vector_type(4))) float float4v;
typedef __attribute__((ext_vector_type(2))) float float2v;

#define TB 3
#define CC 48
#define HH 512
#define WWD 512

static __device__ __forceinline__ unsigned short f2bf(float f) {
  unsigned int u = __builtin_bit_cast(unsigned int, f);
  u += 0x7FFFu + ((u >> 16) & 1u);   // round-to-nearest-even
  return (unsigned short)(u >> 16);
}

__global__ __launch_bounds__(512, 2)
void fpb_fused(const float* __restrict__ x, const float* __restrict__ Ws,
               const float* __restrict__ Hsm, const float* __restrict__ Cs,
               float* __restrict__ out) {
  // XCD swizzle: co-locate the 4 W'-tiles of each window on one XCD.
  int wid = (blockIdx.x & 7) * 128 + (blockIdx.x >> 3);
  int window = wid >> 2;        // 0..255
  int tile   = wid & 3;         // 0..3
  int b = window >> 6;
  int p = (window >> 3) & 7;
  int q = window & 7;
  int j0 = tile * 16;           // W' columns j0..j0+15

  int tid  = threadIdx.x;
  int lane = tid & 63;
  int wave = tid >> 6;          // 0..7
  int lq   = lane >> 4;         // 0..3
  int lc   = lane & 15;         // 0..15
  int mt   = wave & 3;          // this wave's m-tile (h-tile in A, H'-tile in B)

  __shared__ unsigned short Xs[4][64 * 64];   // bf16, elem idx swizzled ^((h&7)<<3)
  __shared__ unsigned short Y1[4][16 * 72];   // [W''][72] h-fast bf16, padded
  __shared__ float          Zs[4][64 * 17];   // [H'][17] f32, padded

  // Preload factor fragments into registers (per wave; tiny, L2-hot).
  short8 wsf[TB][2], hsf[TB][2];
  #pragma unroll
  for (int t = 0; t < TB; ++t) {
    #pragma unroll
    for (int s = 0; s < 2; ++s) {
      short8 aa, bb;
      #pragma unroll
      for (int e = 0; e < 8; ++e) {
        int k = 32 * s + 8 * lq + e;
        aa[e] = (short)f2bf(Ws [t * 4096 + k * 64 + (j0 + lc)]);       // B-frag: Ws[w][W']
        bb[e] = (short)f2bf(Hsm[t * 4096 + k * 64 + (16 * mt + lc)]);  // A-frag: Hs^T[H'][h]
      }
      wsf[t][s] = aa;
      hsf[t][s] = bb;
    }
  }

  float2v acc[CC];
  #pragma unroll
  for (int i = 0; i < CC; ++i) acc[i] = float2v{0.f, 0.f};

  int hA = tid >> 4;    // H'a (0..31); pair row = hA+32
  int wA = tid & 15;    // W''

  const float* xwin = x + (((size_t)b * CC) * HH + p * 64) * WWD + q * 64;

  for (int quad = 0; quad < 12; ++quad) {
    __syncthreads();
    // ---- load 4 c-slices (quad*4 .. +3) into Xs, f32 -> bf16, swizzled ----
    {
      int cs = tid >> 7;            // 0..3
      int r2 = tid & 127;
      int h  = r2 >> 1;             // 0..63
      int w0 = (r2 & 1) * 32;
      const float* src = xwin + ((size_t)(quad * 4 + cs) * HH + h) * WWD + w0;
      unsigned short* dst = Xs[cs];
      int sw = (h & 7) << 3;
      #pragma unroll
      for (int k8 = 0; k8 < 4; ++k8) {
        float4v f0 = *reinterpret_cast<const float4v*>(src + k8 * 8);
        float4v f1 = *reinterpret_cast<const float4v*>(src + k8 * 8 + 4);
        short8 v;
        v[0] = (short)f2bf(f0[0]); v[1] = (short)f2bf(f0[1]);
        v[2] = (short)f2bf(f0[2]); v[3] = (short)f2bf(f0[3]);
        v[4] = (short)f2bf(f1[0]); v[5] = (short)f2bf(f1[1]);
        v[6] = (short)f2bf(f1[2]); v[7] = (short)f2bf(f1[3]);
        int idx = (h * 64 + w0 + k8 * 8) ^ sw;
        *reinterpret_cast<short8*>(&dst[idx]) = v;
      }
    }
    __syncthreads();

    #pragma unroll
    for (int t = 0; t < TB; ++t) {
      // ---- A phase: Y1[h][W''] = X_c @ Ws_t  (contract w) ----
      #pragma unroll
      for (int rep = 0; rep < 2; ++rep) {
        int job = wave + 8 * rep;      // (c_local, mt) with job&3 == wave&3
        int cl4 = job >> 2;            // 0..3
        int h0  = 16 * mt + lc;        // A row
        int sw  = (h0 & 7) << 3;
        float4v d = {0.f, 0.f, 0.f, 0.f};
        #pragma unroll
        for (int s = 0; s < 2; ++s) {
          int idx = (h0 * 64 + 32 * s + 8 * lq) ^ sw;
          short8 afrag = *reinterpret_cast<const short8*>(&Xs[cl4][idx]);
          d = __builtin_amdgcn_mfma_f32_16x16x32_bf16(afrag, wsf[t][s], d, 0, 0, 0);
        }
        // D rows h = 16*mt + 4*lq + r, col W''=lc; pack 4 bf16, h-fast store
        short4v pv;
        pv[0] = (short)f2bf(d[0]); pv[1] = (short)f2bf(d[1]);
        pv[2] = (short)f2bf(d[2]); pv[3] = (short)f2bf(d[3]);
        int oidx = lc * 72 + 16 * mt + 4 * lq;
        *reinterpret_cast<short4v*>(&Y1[cl4][oidx]) = pv;
      }
      __syncthreads();

      // ---- B phase: Z[H'][W''] = Hs_t^T @ Y1  (contract h) ----
      #pragma unroll
      for (int rep = 0; rep < 2; ++rep) {
        int job = wave + 8 * rep;
        int cl4 = job >> 2;
        float4v d = {0.f, 0.f, 0.f, 0.f};
        #pragma unroll
        for (int s = 0; s < 2; ++s) {
          int idx = lc * 72 + 32 * s + 8 * lq;     // B[k=h][col=W'']
          short8 bfrag = *reinterpret_cast<const short8*>(&Y1[cl4][idx]);
          d = __builtin_amdgcn_mfma_f32_16x16x32_bf16(hsf[t][s], bfrag, d, 0, 0, 0);
        }
        int H0 = 16 * mt + 4 * lq;
        #pragma unroll
        for (int r = 0; r < 4; ++r)
          Zs[cl4][(H0 + r) * 17 + lc] = d[r];
      }
      __syncthreads();

      // ---- C phase: acc[C'] += Cs[t][c][C'] * Z (contract c, VALU) ----
      #pragma unroll
      for (int cs = 0; cs < 4; ++cs) {
        float2v z;
        z[0] = Zs[cs][hA * 17 + wA];
        z[1] = Zs[cs][(hA + 32) * 17 + wA];
        const float* csr = Cs + ((size_t)t * CC + (quad * 4 + cs)) * CC;  // uniform -> s_load
        #pragma unroll
        for (int cp = 0; cp < CC; ++cp) {
          acc[cp] += z * csr[cp];
        }
      }
      __syncthreads();
    }
  }

  // ---- epilogue: write out ----
  float* obase = out + (((size_t)b * CC) * HH + p * 64) * WWD + q * 64 + j0;
  #pragma unroll 4
  for (int cp = 0; cp < CC; ++cp) {
    float* o = obase + (size_t)cp * HH * WWD;
    o[(size_t)hA * WWD + wA]        = acc[cp][0];
    o[(size_t)(hA + 32) * WWD + wA] = acc[cp][1];
  }
}

extern "C" void kernel_launch(void* const* d_in, const int* in_sizes, int n_in,
                              void* d_out, int out_size, void* d_ws, size_t ws_size,
                              hipStream_t stream) {
  (void)in_sizes; (void)n_in; (void)d_ws; (void)ws_size; (void)out_size;
  const float* x   = (const float*)d_in[0];
  const float* Ws  = (const float*)d_in[1];
  const float* Hsm = (const float*)d_in[2];
  const float* Cs  = (const float*)d_in[3];
  float* out = (float*)d_out;
  fpb_fused<<<dim3(1024), dim3(512), 0, stream>>>(x, Ws, Hsm, Cs, out);
}

// Round 2
// 213.355 us; speedup vs baseline: 6.8601x; 6.8601x over previous
//
#include <hip/hip_runtime.h>

// FeatureProcessingBlock: per 64x64 window, Out = sum_t Cs_t^T ( Hs_t^T @ X_c @ Ws_t )
// x:(4,48,512,512) f32, Ws/Hs:(3,64,64), Cs:(3,48,48), out f32.
// wg = (window, W''-tile of 16), 512 thr. All three contractions on MFMA 16x16x32 bf16.
// C-contraction K-axis: slot k = t*8 + c_local (chunk of 8 c), slots 24..31 zero-stubbed.

typedef __attribute__((ext_vector_type(8))) short short8;
typedef __attribute__((ext_vector_type(4))) short short4v;
typedef __attribute__((ext_vector_type(4))) float float4v;

#define SMEM_BYTES 142352
// layout: Xs [2][4][4096] bf16 @0 (65536 B) | Y1 [3][4][1152] bf16 @65536 (27648 B)
//         Zb [1024][24] bf16 @93184 (49152 B) | z16 [8] @142336 (16 B)

static __device__ __forceinline__ unsigned short f2bf(float f) {
  unsigned int u = __builtin_bit_cast(unsigned int, f);
  u += 0x7FFFu + ((u >> 16) & 1u);   // RNE
  return (unsigned short)(u >> 16);
}

__global__ __launch_bounds__(512, 2)
void fpb2(const float* __restrict__ x, const float* __restrict__ Ws,
          const float* __restrict__ Hsm, const float* __restrict__ Cs,
          float* __restrict__ out) {
  extern __shared__ char smem[];
  unsigned short* Xs  = (unsigned short*)smem;
  unsigned short* Y1  = (unsigned short*)(smem + 65536);
  char*           ZbB = smem + 93184;
  unsigned short* z16 = (unsigned short*)(smem + 142336);

  int wid = (blockIdx.x & 7) * 128 + (blockIdx.x >> 3);  // XCD swizzle
  int window = wid >> 2, tile = wid & 3;
  int b = window >> 6, p = (window >> 3) & 7, q = window & 7;
  int j0 = tile * 16;

  int tid = threadIdx.x, lane = tid & 63, wave = tid >> 6;
  int lq = lane >> 4, lc = lane & 15;
  int mt  = wave & 3;     // m-tile for A/B stages
  int cpA = wave >> 2;    // A-stage: c in {cpA, cpA+2}
  int cpB = wave >> 2;    // B-stage: c pair {2cpB, 2cpB+1}

  if (tid < 8) z16[tid] = 0;

  // factor fragments (persistent registers)
  short8 wsf[3][2], hsf[3][2];
  #pragma unroll
  for (int t = 0; t < 3; ++t)
    #pragma unroll
    for (int sv = 0; sv < 2; ++sv) {
      short8 aa, bb;
      #pragma unroll
      for (int e = 0; e < 8; ++e) {
        int k = 32 * sv + 8 * lq + e;
        aa[e] = (short)f2bf(Ws [t * 4096 + k * 64 + j0 + lc]);      // B-frag: Ws[w][W']
        bb[e] = (short)f2bf(Hsm[t * 4096 + k * 64 + 16 * mt + lc]); // A-frag: Hs^T[H'][h]
      }
      wsf[t][sv] = aa; hsf[t][sv] = bb;
    }

  float4v acc[3][8];
  #pragma unroll
  for (int m = 0; m < 3; ++m)
    #pragma unroll
    for (int i = 0; i < 8; ++i) acc[m][i] = float4v{0.f, 0.f, 0.f, 0.f};

  // staging geometry: thread -> (c-slice, h, w-half)
  int scs = tid >> 7;
  int sh  = (tid & 127) >> 1;
  int sw0 = (tid & 1) * 32;
  int ssw = (sh & 7) << 3;
  const float* xwin = x + (((size_t)b * 48) * 512 + p * 64) * 512 + q * 64;

  float4v fin[8];
  // prologue: stage sub 0 into Xs[0]
  {
    const float* src = xwin + ((size_t)scs * 512 + sh) * 512 + sw0;
    #pragma unroll
    for (int k8 = 0; k8 < 4; ++k8) {
      fin[2 * k8]     = *(const float4v*)(src + 8 * k8);
      fin[2 * k8 + 1] = *(const float4v*)(src + 8 * k8 + 4);
    }
    unsigned short* dst = Xs + scs * 4096;
    #pragma unroll
    for (int k8 = 0; k8 < 4; ++k8) {
      short8 v;
      #pragma unroll
      for (int e2 = 0; e2 < 4; ++e2) {
        v[e2]     = (short)f2bf(fin[2 * k8][e2]);
        v[4 + e2] = (short)f2bf(fin[2 * k8 + 1][e2]);
      }
      *(short8*)&dst[(sh * 64 + sw0 + 8 * k8) ^ ssw] = v;
    }
  }

  for (int s = 0; s < 12; ++s) {        // sub = 4 c-slices; chunk = 2 subs
    int buf = s & 1;
    __syncthreads();                    // Xs[buf] ready; C-reads of Zb done

    if (s < 11) {                       // T14: issue next-sub loads early
      const float* src = xwin + ((size_t)((s + 1) * 4 + scs) * 512 + sh) * 512 + sw0;
      #pragma unroll
      for (int k8 = 0; k8 < 4; ++k8) {
        fin[2 * k8]     = *(const float4v*)(src + 8 * k8);
        fin[2 * k8 + 1] = *(const float4v*)(src + 8 * k8 + 4);
      }
    }

    // ---- A-phase: Y1[t][c] = X_c @ Ws_t (contract w); X-frag reused over t ----
    {
      int h0 = 16 * mt + lc, swz = (h0 & 7) << 3;
      #pragma unroll
      for (int cj = 0; cj < 2; ++cj) {
        int c = cpA + 2 * cj;
        const unsigned short* bsrc = Xs + buf * 16384 + c * 4096;
        short8 a0 = *(const short8*)&bsrc[(h0 * 64 + 8 * lq) ^ swz];
        short8 a1 = *(const short8*)&bsrc[(h0 * 64 + 32 + 8 * lq) ^ swz];
        #pragma unroll
        for (int t = 0; t < 3; ++t) {
          float4v d = {0.f, 0.f, 0.f, 0.f};
          d = __builtin_amdgcn_mfma_f32_16x16x32_bf16(a0, wsf[t][0], d, 0, 0, 0);
          d = __builtin_amdgcn_mfma_f32_16x16x32_bf16(a1, wsf[t][1], d, 0, 0, 0);
          short4v pv;
          pv[0] = (short)f2bf(d[0]); pv[1] = (short)f2bf(d[1]);
          pv[2] = (short)f2bf(d[2]); pv[3] = (short)f2bf(d[3]);
          *(short4v*)&Y1[(t * 4 + c) * 1152 + lc * 72 + 16 * mt + 4 * lq] = pv;
        }
      }
    }
    __syncthreads();

    // ---- B-phase: Zb[px][k] = Hs_t^T @ Y1 (contract h); paired bf16 writes ----
    {
      int c0 = 2 * cpB;
      #pragma unroll
      for (int t = 0; t < 3; ++t) {
        float4v d0 = {0.f, 0.f, 0.f, 0.f}, d1 = {0.f, 0.f, 0.f, 0.f};
        {
          const unsigned short* ys = &Y1[(t * 4 + c0) * 1152 + lc * 72 + 8 * lq];
          short8 y0 = *(const short8*)(ys);
          short8 y1v = *(const short8*)(ys + 32);
          d0 = __builtin_amdgcn_mfma_f32_16x16x32_bf16(hsf[t][0], y0, d0, 0, 0, 0);
          d0 = __builtin_amdgcn_mfma_f32_16x16x32_bf16(hsf[t][1], y1v, d0, 0, 0, 0);
        }
        {
          const unsigned short* ys = &Y1[(t * 4 + c0 + 1) * 1152 + lc * 72 + 8 * lq];
          short8 y0 = *(const short8*)(ys);
          short8 y1v = *(const short8*)(ys + 32);
          d1 = __builtin_amdgcn_mfma_f32_16x16x32_bf16(hsf[t][0], y0, d1, 0, 0, 0);
          d1 = __builtin_amdgcn_mfma_f32_16x16x32_bf16(hsf[t][1], y1v, d1, 0, 0, 0);
        }
        int k0 = t * 8 + (s & 1) * 4 + 2 * cpB;
        #pragma unroll
        for (int r = 0; r < 4; ++r) {
          int px = (16 * mt + 4 * lq + r) * 16 + lc;
          unsigned int vv = (unsigned int)f2bf(d0[r]) | ((unsigned int)f2bf(d1[r]) << 16);
          *(unsigned int*)(ZbB + px * 48 + k0 * 2) = vv;
        }
      }
      if (s < 11) {   // write staged X for next sub (latency hidden under A+B)
        unsigned short* dst = Xs + (buf ^ 1) * 16384 + scs * 4096;
        #pragma unroll
        for (int k8 = 0; k8 < 4; ++k8) {
          short8 v;
          #pragma unroll
          for (int e2 = 0; e2 < 4; ++e2) {
            v[e2]     = (short)f2bf(fin[2 * k8][e2]);
            v[4 + e2] = (short)f2bf(fin[2 * k8 + 1][e2]);
          }
          *(short8*)&dst[(sh * 64 + sw0 + 8 * k8) ^ ssw] = v;
        }
      }
    }

    if (s & 1) {
      __syncthreads();
      // ---- C-phase: acc += Cs^T @ Zb (contract t,c; K=32, slots 24..31 zero) ----
      int c0 = (s >> 1) * 8;
      short8 csf[3];
      if (lq < 3) {
        #pragma unroll
        for (int m = 0; m < 3; ++m) {
          short8 a;
          #pragma unroll
          for (int e = 0; e < 8; ++e)
            a[e] = (short)f2bf(Cs[lq * 2304 + (c0 + e) * 48 + 16 * m + lc]);
          csf[m] = a;
        }
      } else {
        #pragma unroll
        for (int m = 0; m < 3; ++m) {
          short8 a;
          #pragma unroll
          for (int e = 0; e < 8; ++e) a[e] = 0;
          csf[m] = a;
        }
      }
      #pragma unroll
      for (int i = 0; i < 8; ++i) {
        int n = wave + 8 * i;
        const unsigned short* zsrc =
            (lq < 3) ? (const unsigned short*)(ZbB + (16 * n + lc) * 48 + 16 * lq) : z16;
        short8 zf = *(const short8*)zsrc;
        #pragma unroll
        for (int m = 0; m < 3; ++m)
          acc[m][i] = __builtin_amdgcn_mfma_f32_16x16x32_bf16(csf[m], zf, acc[m][i], 0, 0, 0);
      }
    }
  }

  // ---- epilogue: fully static-indexed stores ----
  #pragma unroll
  for (int m = 0; m < 3; ++m)
    #pragma unroll
    for (int i = 0; i < 8; ++i) {
      int n = wave + 8 * i;
      size_t rowbase = (((size_t)(b * 48 + 16 * m + 4 * lq)) * 512 + p * 64 + n) * 512
                       + q * 64 + j0 + lc;
      #pragma unroll
      for (int r = 0; r < 4; ++r)
        out[rowbase + (size_t)r * 262144] = acc[m][i][r];
    }
}

extern "C" void kernel_launch(void* const* d_in, const int* in_sizes, int n_in,
                              void* d_out, int out_size, void* d_ws, size_t ws_size,
                              hipStream_t stream) {
  (void)in_sizes; (void)n_in; (void)d_ws; (void)ws_size; (void)out_size;
  const float* x   = (const float*)d_in[0];
  const float* Ws  = (const float*)d_in[1];
  const float* Hsm = (const float*)d_in[2];
  const float* Cs  = (const float*)d_in[3];
  float* out = (float*)d_out;
  (void)hipFuncSetAttribute((const void*)fpb2,
                            hipFuncAttributeMaxDynamicSharedMemorySize, SMEM_BYTES);
  fpb2<<<dim3(1024), dim3(512), SMEM_BYTES, stream>>>(x, Ws, Hsm, Cs, out);
}

// Round 3
// 176.306 us; speedup vs baseline: 8.3017x; 1.2101x over previous
//
#include <hip/hip_runtime.h>
#include <hip/hip_bf16.h>

// FeatureProcessingBlock: per 64x64 window, Out = sum_t Cs_t^T ( Hs_t^T @ X_c @ Ws_t )
// x:(4,48,512,512) f32, Ws/Hs:(3,64,64), Cs:(3,48,48), out f32.
// wg = (window, W''-tile16), 512 thr. All contractions MFMA 16x16x32 bf16.
// R3: no X staging (direct global->frag + 1-deep prefetch), Cs frags in LDS,
//     Zb 32B rows + slot-XOR (kills 16-way conflicts), 2 barriers/iter.

typedef __attribute__((ext_vector_type(8))) short short8;
typedef __attribute__((ext_vector_type(4))) short short4v;
typedef __attribute__((ext_vector_type(4))) float float4v;

#define SMEM_BYTES 97280
// Y1 @0 (27648 B, bf16 [12][16*72]) | Zb @27648 (32768 B, [1024 px][32 B])
// Cf @60416 (36864 B, csf frags [12 s][3 m][64 lane][16 B])

static __device__ __forceinline__ unsigned short f2bf(float f) {
  return __builtin_bit_cast(unsigned short, __float2bfloat16(f));
}
static __device__ __forceinline__ unsigned int pk2(float a, float b) {
  return (unsigned int)f2bf(a) | ((unsigned int)f2bf(b) << 16);
}

__global__ __launch_bounds__(512, 2)
void fpb3(const float* __restrict__ x, const float* __restrict__ Ws,
          const float* __restrict__ Hsm, const float* __restrict__ Cs,
          float* __restrict__ out) {
  extern __shared__ char smem[];
  unsigned short* Y1 = (unsigned short*)smem;
  char*           Zb = smem + 27648;
  unsigned short* Cf = (unsigned short*)(smem + 60416);

  int wid = (blockIdx.x & 7) * 128 + (blockIdx.x >> 3);  // XCD swizzle
  int window = wid >> 2, tile = wid & 3;
  int b = window >> 6, p = (window >> 3) & 7, q = window & 7;
  int j0 = tile * 16;

  int tid = threadIdx.x, lane = tid & 63, wave = tid >> 6;
  int lq = lane >> 4, lc = lane & 15;
  int mt = wave & 3, cp = wave >> 2;     // B-phase roles
  int jg = (lc >> 2) & 1;                // Zb slot-swizzle bit (per-thread const)

  // ---- init: Cs fragments -> LDS (final lane layout; zeros baked for k>=12) ----
  for (int idx = wave; idx < 36; idx += 8) {
    int ss = idx / 3, m = idx - 3 * (idx / 3);
    short8 v;
    #pragma unroll
    for (int e = 0; e < 8; ++e) {
      int k = 8 * lq + e;
      unsigned short u = 0;
      if (k < 12) {
        int cl = k / 3, t = k - 3 * cl;          // slot k = cl*3 + t
        u = f2bf(Cs[t * 2304 + (4 * ss + cl) * 48 + 16 * m + lc]);
      }
      v[e] = (short)u;
    }
    *(short8*)&Cf[((ss * 3 + m) * 64 + lane) * 8] = v;
  }
  // ---- init: Zb pad slots 12..15 (logical bytes 24..31) = 0, persistent ----
  {
    int px0 = tid, px1 = tid + 512;
    *(unsigned long long*)(Zb + px0 * 32 + ((1 ^ ((px0 >> 2) & 1)) << 4) + 8) = 0ull;
    *(unsigned long long*)(Zb + px1 * 32 + ((1 ^ ((px1 >> 2) & 1)) << 4) + 8) = 0ull;
  }

  // ---- factor fragments (persistent regs) ----
  short8 wsf[3][2], hsf[3][2];
  #pragma unroll
  for (int t = 0; t < 3; ++t)
    #pragma unroll
    for (int sv = 0; sv < 2; ++sv) {
      short8 aa, bb;
      #pragma unroll
      for (int e = 0; e < 8; ++e) {
        int k = 32 * sv + 8 * lq + e;
        aa[e] = (short)f2bf(Ws [t * 4096 + k * 64 + j0 + lc]);      // B-frag Ws[w][W']
        bb[e] = (short)f2bf(Hsm[t * 4096 + k * 64 + 16 * mt + lc]); // A-frag Hs^T[H'][h]
      }
      wsf[t][sv] = aa; hsf[t][sv] = bb;
    }

  float4v acc[3][8];
  #pragma unroll
  for (int m = 0; m < 3; ++m)
    #pragma unroll
    for (int i = 0; i < 8; ++i) acc[m][i] = float4v{0.f, 0.f, 0.f, 0.f};

  const float* xwin = x + (((size_t)b * 48) * 512 + p * 64) * 512 + q * 64;
  int mA0 = wave >> 2, mA1 = mA0 + 2, cAl = wave & 3;   // A-phase roles
  const float* sA0 = xwin + ((size_t)(16 * mA0 + lc)) * 512 + 8 * lq;
  const float* sA1 = xwin + ((size_t)(16 * mA1 + lc)) * 512 + 8 * lq;

  float4v fin[8];
  {
    size_t co = (size_t)cAl * 262144;
    fin[0] = *(const float4v*)(sA0 + co);      fin[1] = *(const float4v*)(sA0 + co + 4);
    fin[2] = *(const float4v*)(sA0 + co + 32); fin[3] = *(const float4v*)(sA0 + co + 36);
    fin[4] = *(const float4v*)(sA1 + co);      fin[5] = *(const float4v*)(sA1 + co + 4);
    fin[6] = *(const float4v*)(sA1 + co + 32); fin[7] = *(const float4v*)(sA1 + co + 36);
  }

  __syncthreads();   // Cf + Zb pad ready

  for (int s = 0; s < 12; ++s) {
    // ---- A: Y1[t][cAl] = X_c @ Ws_t (contract w), frags direct from global ----
    #pragma unroll
    for (int rep = 0; rep < 2; ++rep) {
      short8 a0, a1;
      #pragma unroll
      for (int e2 = 0; e2 < 4; ++e2) {
        a0[e2]     = (short)f2bf(fin[4 * rep + 0][e2]);
        a0[4 + e2] = (short)f2bf(fin[4 * rep + 1][e2]);
        a1[e2]     = (short)f2bf(fin[4 * rep + 2][e2]);
        a1[4 + e2] = (short)f2bf(fin[4 * rep + 3][e2]);
      }
      int mA = (rep == 0) ? mA0 : mA1;
      #pragma unroll
      for (int t = 0; t < 3; ++t) {
        float4v d = {0.f, 0.f, 0.f, 0.f};
        d = __builtin_amdgcn_mfma_f32_16x16x32_bf16(a0, wsf[t][0], d, 0, 0, 0);
        d = __builtin_amdgcn_mfma_f32_16x16x32_bf16(a1, wsf[t][1], d, 0, 0, 0);
        short4v pv;
        pv[0] = (short)f2bf(d[0]); pv[1] = (short)f2bf(d[1]);
        pv[2] = (short)f2bf(d[2]); pv[3] = (short)f2bf(d[3]);
        *(short4v*)&Y1[(t * 4 + cAl) * 1152 + lc * 72 + 16 * mA + 4 * lq] = pv;
      }
    }
    if (s < 11) {   // prefetch next c-quad's fragments (regs, no barrier dep)
      size_t co = (size_t)(4 * s + 4 + cAl) * 262144;
      fin[0] = *(const float4v*)(sA0 + co);      fin[1] = *(const float4v*)(sA0 + co + 4);
      fin[2] = *(const float4v*)(sA0 + co + 32); fin[3] = *(const float4v*)(sA0 + co + 36);
      fin[4] = *(const float4v*)(sA1 + co);      fin[5] = *(const float4v*)(sA1 + co + 4);
      fin[6] = *(const float4v*)(sA1 + co + 32); fin[7] = *(const float4v*)(sA1 + co + 36);
    }
    __syncthreads();

    // ---- B: Zb[px][k=cl*3+t] = Hs_t^T @ Y1 (contract h); packed swizzled writes ----
    {
      float4v d[3][2];
      #pragma unroll
      for (int t = 0; t < 3; ++t)
        #pragma unroll
        for (int cj = 0; cj < 2; ++cj) {
          const unsigned short* ys = &Y1[(t * 4 + 2 * cp + cj) * 1152 + lc * 72 + 8 * lq];
          short8 y0 = *(const short8*)(ys);
          short8 y1 = *(const short8*)(ys + 32);
          float4v dd = {0.f, 0.f, 0.f, 0.f};
          dd = __builtin_amdgcn_mfma_f32_16x16x32_bf16(hsf[t][0], y0, dd, 0, 0, 0);
          dd = __builtin_amdgcn_mfma_f32_16x16x32_bf16(hsf[t][1], y1, dd, 0, 0, 0);
          d[t][cj] = dd;
        }
      #pragma unroll
      for (int r = 0; r < 4; ++r) {
        int px = (16 * mt + 4 * lq + r) * 16 + lc;
        char* row = Zb + px * 32;
        unsigned int w0 = pk2(d[0][0][r], d[1][0][r]);
        unsigned int w1 = pk2(d[2][0][r], d[0][1][r]);
        unsigned int w2 = pk2(d[1][1][r], d[2][1][r]);
        if (cp == 0) {          // logical bytes 0..11
          char* g0 = row + ((0 ^ jg) << 4);
          *(unsigned long long*)g0 =
              (unsigned long long)w0 | ((unsigned long long)w1 << 32);
          *(unsigned int*)(g0 + 8) = w2;
        } else {                // logical bytes 12..23
          *(unsigned int*)(row + ((0 ^ jg) << 4) + 12) = w0;
          char* g1 = row + ((1 ^ jg) << 4);
          *(unsigned long long*)g1 =
              (unsigned long long)w1 | ((unsigned long long)w2 << 32);
        }
      }
    }
    __syncthreads();

    // ---- C: acc += Cs-frag @ Zb (contract t,c; K slots 12..15 zero) ----
    {
      short8 cf0 = *(const short8*)&Cf[((s * 3 + 0) * 64 + lane) * 8];
      short8 cf1 = *(const short8*)&Cf[((s * 3 + 1) * 64 + lane) * 8];
      short8 cf2 = *(const short8*)&Cf[((s * 3 + 2) * 64 + lane) * 8];
      #pragma unroll
      for (int i = 0; i < 8; ++i) {
        int px = 16 * (wave + 8 * i) + lc;
        short8 zf = *(const short8*)(Zb + px * 32 + (((lq & 1) ^ jg) << 4));
        acc[0][i] = __builtin_amdgcn_mfma_f32_16x16x32_bf16(cf0, zf, acc[0][i], 0, 0, 0);
        acc[1][i] = __builtin_amdgcn_mfma_f32_16x16x32_bf16(cf1, zf, acc[1][i], 0, 0, 0);
        acc[2][i] = __builtin_amdgcn_mfma_f32_16x16x32_bf16(cf2, zf, acc[2][i], 0, 0, 0);
      }
    }
    // no barrier: next A touches Y1/global only; Zb reuse guarded by next syncthreads
  }

  // ---- epilogue: fully static stores ----
  #pragma unroll
  for (int m = 0; m < 3; ++m)
    #pragma unroll
    for (int i = 0; i < 8; ++i) {
      int n = wave + 8 * i;
      size_t rowbase = (((size_t)(b * 48 + 16 * m + 4 * lq)) * 512 + p * 64 + n) * 512
                       + q * 64 + j0 + lc;
      #pragma unroll
      for (int r = 0; r < 4; ++r)
        out[rowbase + (size_t)r * 262144] = acc[m][i][r];
    }
}

extern "C" void kernel_launch(void* const* d_in, const int* in_sizes, int n_in,
                              void* d_out, int out_size, void* d_ws, size_t ws_size,
                              hipStream_t stream) {
  (void)in_sizes; (void)n_in; (void)d_ws; (void)ws_size; (void)out_size;
  const float* x   = (const float*)d_in[0];
  const float* Ws  = (const float*)d_in[1];
  const float* Hsm = (const float*)d_in[2];
  const float* Cs  = (const float*)d_in[3];
  float* out = (float*)d_out;
  (void)hipFuncSetAttribute((const void*)fpb3,
                            hipFuncAttributeMaxDynamicSharedMemorySize, SMEM_BYTES);
  fpb3<<<dim3(1024), dim3(512), SMEM_BYTES, stream>>>(x, Ws, Hsm, Cs, out);
}

// Round 4
// 162.020 us; speedup vs baseline: 9.0337x; 1.0882x over previous
//
#include <hip/hip_runtime.h>
#include <hip/hip_bf16.h>

// FeatureProcessingBlock: per 64x64 window, Out = sum_t Cs_t^T ( Hs_t^T @ X_c @ Ws_t )
// R4: chunk = 8 c (6 chunks, 12 barriers), K-slot order k=t*8+cl (C-phase t==lq),
//     Zb 48B rows (bank-even reads), compact Cf, full-cover 2-slot prefetch.

typedef __attribute__((ext_vector_type(8))) short short8;
typedef __attribute__((ext_vector_type(4))) short short4v;
typedef __attribute__((ext_vector_type(4))) float float4v;

#define SMEM_BYTES 118288
// Y1 @0: [3t*8c][16lc x 72h] bf16 = 55296 | Zb @55296: [1024 px][48 B] = 49152
// Cf @104448: [18 ss*m][16 lc][48 B] = 13824 | z16 @118272: 16 B zeros

static __device__ __forceinline__ unsigned short f2bf(float f) {
  return __builtin_bit_cast(unsigned short, __float2bfloat16(f));
}
static __device__ __forceinline__ unsigned long long pk4(float a, float b, float c, float d) {
  unsigned long long lo = (unsigned int)((unsigned int)f2bf(a) | ((unsigned int)f2bf(b) << 16));
  unsigned long long hi = (unsigned int)((unsigned int)f2bf(c) | ((unsigned int)f2bf(d) << 16));
  return lo | (hi << 32);
}

__global__ __launch_bounds__(512, 2)
void fpb4(const float* __restrict__ x, const float* __restrict__ Ws,
          const float* __restrict__ Hsm, const float* __restrict__ Cs,
          float* __restrict__ out) {
  extern __shared__ char smem[];
  unsigned short* Y1 = (unsigned short*)smem;
  char* Zb  = smem + 55296;
  char* Cf  = smem + 104448;
  char* z16 = smem + 118272;

  int wid = (blockIdx.x & 7) * 128 + (blockIdx.x >> 3);  // XCD swizzle
  int window = wid >> 2, tile = wid & 3;
  int b = window >> 6, p = (window >> 3) & 7, q = window & 7;
  int j0 = tile * 16;

  int tid = threadIdx.x, lane = tid & 63, wave = tid >> 6;
  int lq = lane >> 4, lc = lane & 15;
  int mt = wave & 3, cp = wave >> 2;

  if (tid < 4) ((unsigned int*)z16)[tid] = 0;

  // Cf init: row (ss*3+m, lc), slot k = t*8+cl -> lane lq holds t=lq, e=cl
  for (int idx = wave; idx < 18; idx += 8) {
    int ss = idx / 3, m = idx - 3 * ss;
    if (lq < 3) {
      short8 v;
      #pragma unroll
      for (int e = 0; e < 8; ++e)
        v[e] = (short)f2bf(Cs[lq * 2304 + (8 * ss + e) * 48 + 16 * m + lc]);
      *(short8*)(Cf + (idx * 16 + lc) * 48 + lq * 16) = v;
    }
  }

  // persistent factor fragments
  short8 wsf[3][2], hsf[3][2];
  #pragma unroll
  for (int t = 0; t < 3; ++t)
    #pragma unroll
    for (int sv = 0; sv < 2; ++sv) {
      short8 aa, bb;
      #pragma unroll
      for (int e = 0; e < 8; ++e) {
        int k = 32 * sv + 8 * lq + e;
        aa[e] = (short)f2bf(Ws [t * 4096 + k * 64 + j0 + lc]);      // B: Ws[w][W']
        bb[e] = (short)f2bf(Hsm[t * 4096 + k * 64 + 16 * mt + lc]); // A: Hs^T[H'][h]
      }
      wsf[t][sv] = aa; hsf[t][sv] = bb;
    }

  float4v acc[3][8];
  #pragma unroll
  for (int m = 0; m < 3; ++m)
    #pragma unroll
    for (int i = 0; i < 8; ++i) acc[m][i] = float4v{0.f, 0.f, 0.f, 0.f};

  // A-stage: wave = c (within chunk); rows 16*mA+lc, cols 8*lq(+32)
  const float* xbase = x + (((size_t)b * 48) * 512 + p * 64) * 512 + q * 64
                         + (size_t)wave * 262144 + (size_t)lc * 512 + 8 * lq;

  float4v fin[2][8];   // two half-chunk prefetch slots (mA pair each)
  #pragma unroll
  for (int h = 0; h < 2; ++h) {
    const float* src = xbase + (size_t)(32 * h) * 512;
    #pragma unroll
    for (int j2 = 0; j2 < 2; ++j2) {
      const float* r = src + (size_t)(16 * j2) * 512;
      fin[h][4*j2+0] = *(const float4v*)(r);
      fin[h][4*j2+1] = *(const float4v*)(r + 4);
      fin[h][4*j2+2] = *(const float4v*)(r + 32);
      fin[h][4*j2+3] = *(const float4v*)(r + 36);
    }
  }

  for (int s = 0; s < 6; ++s) {
    // ---- A: Y1[t][c=wave] = X_c @ Ws_t (contract w) ----
    #pragma unroll
    for (int h = 0; h < 2; ++h) {
      short8 af[4];
      #pragma unroll
      for (int j2 = 0; j2 < 2; ++j2) {
        short8 a0, a1;
        #pragma unroll
        for (int e2 = 0; e2 < 4; ++e2) {
          a0[e2]   = (short)f2bf(fin[h][4*j2+0][e2]);
          a0[4+e2] = (short)f2bf(fin[h][4*j2+1][e2]);
          a1[e2]   = (short)f2bf(fin[h][4*j2+2][e2]);
          a1[4+e2] = (short)f2bf(fin[h][4*j2+3][e2]);
        }
        af[2*j2] = a0; af[2*j2+1] = a1;
      }
      if (s < 5) {  // refill this slot for chunk s+1 (full-chunk latency cover)
        const float* src = xbase + (size_t)(s + 1) * 2097152 + (size_t)(32 * h) * 512;
        #pragma unroll
        for (int j2 = 0; j2 < 2; ++j2) {
          const float* r = src + (size_t)(16 * j2) * 512;
          fin[h][4*j2+0] = *(const float4v*)(r);
          fin[h][4*j2+1] = *(const float4v*)(r + 4);
          fin[h][4*j2+2] = *(const float4v*)(r + 32);
          fin[h][4*j2+3] = *(const float4v*)(r + 36);
        }
      }
      #pragma unroll
      for (int j2 = 0; j2 < 2; ++j2) {
        int mA = 2 * h + j2;
        #pragma unroll
        for (int t = 0; t < 3; ++t) {
          float4v d = {0.f, 0.f, 0.f, 0.f};
          d = __builtin_amdgcn_mfma_f32_16x16x32_bf16(af[2*j2],   wsf[t][0], d, 0, 0, 0);
          d = __builtin_amdgcn_mfma_f32_16x16x32_bf16(af[2*j2+1], wsf[t][1], d, 0, 0, 0);
          short4v pv;
          pv[0] = (short)f2bf(d[0]); pv[1] = (short)f2bf(d[1]);
          pv[2] = (short)f2bf(d[2]); pv[3] = (short)f2bf(d[3]);
          *(short4v*)&Y1[(t * 8 + wave) * 1152 + lc * 72 + 16 * mA + 4 * lq] = pv;
        }
      }
    }
    __syncthreads();

    // ---- B: Zb[px][k=t*8+cl] = Hs_t^T @ Y1 (contract h) ----
    #pragma unroll
    for (int t = 0; t < 3; ++t) {
      float4v dB[4];
      #pragma unroll
      for (int cj = 0; cj < 4; ++cj) {
        const unsigned short* ys = &Y1[(t * 8 + 4 * cp + cj) * 1152 + lc * 72 + 8 * lq];
        short8 y0 = *(const short8*)ys;
        short8 y1 = *(const short8*)(ys + 32);
        float4v dd = {0.f, 0.f, 0.f, 0.f};
        dd = __builtin_amdgcn_mfma_f32_16x16x32_bf16(hsf[t][0], y0, dd, 0, 0, 0);
        dd = __builtin_amdgcn_mfma_f32_16x16x32_bf16(hsf[t][1], y1, dd, 0, 0, 0);
        dB[cj] = dd;
      }
      #pragma unroll
      for (int r = 0; r < 4; ++r) {
        int px = (16 * mt + 4 * lq + r) * 16 + lc;
        *(unsigned long long*)(Zb + px * 48 + 16 * t + 8 * cp) =
            pk4(dB[0][r], dB[1][r], dB[2][r], dB[3][r]);
      }
    }
    __syncthreads();

    // ---- C: acc += Cs-frag @ Zb (contract t,c; K=32, slots 24..31 zero) ----
    {
      short8 cf[3];
      #pragma unroll
      for (int m = 0; m < 3; ++m) {
        const char* csrc = (lq < 3) ? (Cf + ((s * 3 + m) * 16 + lc) * 48 + lq * 16) : z16;
        cf[m] = *(const short8*)csrc;
      }
      #pragma unroll
      for (int i = 0; i < 8; ++i) {
        int px = 16 * (wave + 8 * i) + lc;
        const char* zsrc = (lq < 3) ? (Zb + px * 48 + 16 * lq) : z16;
        short8 zf = *(const short8*)zsrc;
        acc[0][i] = __builtin_amdgcn_mfma_f32_16x16x32_bf16(cf[0], zf, acc[0][i], 0, 0, 0);
        acc[1][i] = __builtin_amdgcn_mfma_f32_16x16x32_bf16(cf[1], zf, acc[1][i], 0, 0, 0);
        acc[2][i] = __builtin_amdgcn_mfma_f32_16x16x32_bf16(cf[2], zf, acc[2][i], 0, 0, 0);
      }
    }
    // no barrier: next A writes Y1 (last read before bar2); C's Zb reads
    // complete before next bar1 orders B's Zb writes.
  }

  // ---- epilogue: fully static stores ----
  #pragma unroll
  for (int m = 0; m < 3; ++m)
    #pragma unroll
    for (int i = 0; i < 8; ++i) {
      int n = wave + 8 * i;
      size_t rowbase = (((size_t)(b * 48 + 16 * m + 4 * lq)) * 512 + p * 64 + n) * 512
                       + q * 64 + j0 + lc;
      #pragma unroll
      for (int r = 0; r < 4; ++r)
        out[rowbase + (size_t)r * 262144] = acc[m][i][r];
    }
}

extern "C" void kernel_launch(void* const* d_in, const int* in_sizes, int n_in,
                              void* d_out, int out_size, void* d_ws, size_t ws_size,
                              hipStream_t stream) {
  (void)in_sizes; (void)n_in; (void)d_ws; (void)ws_size; (void)out_size;
  const float* x   = (const float*)d_in[0];
  const float* Ws  = (const float*)d_in[1];
  const float* Hsm = (const float*)d_in[2];
  const float* Cs  = (const float*)d_in[3];
  float* out = (float*)d_out;
  (void)hipFuncSetAttribute((const void*)fpb4,
                            hipFuncAttributeMaxDynamicSharedMemorySize, SMEM_BYTES);
  fpb4<<<dim3(1024), dim3(512), SMEM_BYTES, stream>>>(x, Ws, Hsm, Cs, out);
}